// Round 10
// baseline (379.922 us; speedup 1.0000x reference)
//
#include <hip/hip_runtime.h>
#include <stdint.h>

// ---------------------------------------------------------------------------
// DynamicConv (CondConv x2 + PReLU + self-routing + 1x1 out), MI355X gfx950
// R10: R6 structure + fn=8 wave tiles (64co x 128pix, 42.7 FLOP/LDS-byte,
//      MFMA-bound) in 3-row/3-wave/192-thr blocks at 78.5KB LDS -> 2 blk/CU.
//      Per-chunk barriers only; sig-swizzle (periodic-16) unchanged.
// ---------------------------------------------------------------------------

typedef _Float16 f16_t;
typedef _Float16 f16x8 __attribute__((ext_vector_type(8)));
typedef _Float16 f16x4 __attribute__((ext_vector_type(4)));
typedef float    f32x4 __attribute__((ext_vector_type(4)));

#define B_   8
#define R_   4
#define C_   64
#define C2_  128
#define H_   128
#define W_   128
#define E_   8
#define RF_  256
#define WP_  130   // padded width  (guard cols at pix 0 and 129)
#define HP_  130   // padded height (guard rows at hp 0 and 129)

__device__ __forceinline__ f32x4 mfma16(f16x8 a, f16x8 b, f32x4 c) {
  return __builtin_amdgcn_mfma_f32_16x16x32_f16(a, b, c, 0, 0, 0);
}

// async global->LDS, 16B per lane; dest wave-linear (base + lane*16)
__device__ __forceinline__ void gl16(const f16_t* g, f16_t* l) {
  __builtin_amdgcn_global_load_lds(
      (const __attribute__((address_space(1))) unsigned int*)(const void*)g,
      (__attribute__((address_space(3))) unsigned int*)(void*)l, 16, 0, 0);
}

__device__ __host__ __forceinline__ int sig(int n) { return (n ^ (n >> 2)) & 3; }

// ---------- routing weights + zero pooled[4][B][C2] ----------
__global__ void k_rw(const float* __restrict__ routing, const float* __restrict__ rW,
                     const float* __restrict__ rB, float* __restrict__ rw,
                     float* __restrict__ pooled4) {
  int t = threadIdx.x;                 // 256 = R*B*E
  #pragma unroll
  for (int i = 0; i < 16; ++i) pooled4[i*256 + t] = 0.f;
  int e = t & 7, b = (t >> 3) & 7, r = t >> 6;
  float acc = rB[e];
  for (int f = 0; f < RF_; ++f)
    acc += routing[(b*R_ + r)*RF_ + f] * rW[f*E_ + e];
  rw[(r*B_ + b)*E_ + e] = 1.0f / (1.0f + __expf(-acc));
}

// ---------- zero guard rows/cols of xbt and all-r xct (130x130) --------------
__global__ void k_zero(f16_t* __restrict__ xbt, f16_t* __restrict__ xct,
                       size_t xct_stride) {
  const f16x8 z = {0,0,0,0,0,0,0,0};
  int t = blockIdx.x*256 + threadIdx.x;
  if (t < 16640) {                       // xbt guard rows: 8b*2*130pix*8slots
    int ch = t & 7, u = t >> 3;
    int pix = u % 130; u /= 130;
    int rs = u & 1, b = u >> 1;
    *(f16x8*)&xbt[((size_t)(b*HP_ + rs*129)*WP_ + pix)*C_ + ch*8] = z;
    return;
  }
  t -= 16640;
  if (t < 133120) {                      // xct guard rows: 4r*8b*2*130pix*16slots
    int ch = t & 15, u = t >> 4;
    int pix = u % 130; u /= 130;
    int rs = u & 1; u >>= 1;
    int b = u & 7, r = u >> 3;
    *(f16x8*)&xct[(size_t)r*xct_stride + ((size_t)(b*HP_ + rs*129)*WP_ + pix)*C2_ + ch*8] = z;
    return;
  }
  t -= 133120;
  if (t < 131072) {                      // xct guard cols: 4r*8b*128row*2*16slots
    int ch = t & 15, u = t >> 4;
    int hp = (u & 127) + 1; u >>= 7;
    int cs = u & 1; u >>= 1;
    int b = u & 7, r = u >> 3;
    *(f16x8*)&xct[(size_t)r*xct_stride + ((size_t)(b*HP_ + hp)*WP_ + cs*129)*C2_ + ch*8] = z;
  }
}

// ---------- x: NCHW f32 -> padded NHWC f16 (interior rows; guard cols) ------
__global__ void k_xt(const float* __restrict__ x, f16_t* __restrict__ xbt) {
  int wh = blockIdx.x, h = blockIdx.y, b = blockIdx.z;
  int t = threadIdx.x;
  int w0 = wh * 64;
  __shared__ float tile[64][65];
  #pragma unroll
  for (int rep = 0; rep < 16; ++rep) {
    int idx = rep*256 + t;
    int c = idx >> 6, w = idx & 63;
    tile[c][w] = x[((size_t)(b*C_ + c)*H_ + h)*W_ + w0 + w];
  }
  __syncthreads();
  #pragma unroll
  for (int rep = 0; rep < 16; ++rep) {
    int idx = rep*256 + t;
    int w = idx >> 6, c = idx & 63;
    xbt[((size_t)(b*HP_ + h + 1)*WP_ + (w0 + w + 1))*C_ + c] = (f16_t)tile[c][w];
  }
  if (t < 64) {
    if (wh == 0) xbt[((size_t)(b*HP_ + h + 1)*WP_ + 0)*C_ + t]   = (f16_t)0.0f;
    else         xbt[((size_t)(b*HP_ + h + 1)*WP_ + 129)*C_ + t] = (f16_t)0.0f;
  }
}

// ---------- mix1: w1m row = ((rb*2+coh)*2+cb)*64+co6, 288 f16/row -----------
__global__ void k_mix1(const float* __restrict__ rw, const float* __restrict__ W1,
                       f16_t* __restrict__ w1m) {
  int gid = blockIdx.x*256 + threadIdx.x;    // 589824 total
  int cq4 = gid & 15;                        // ch quad: ch = cq4*4 .. +3
  int s   = (gid >> 4) % 9;
  int t2  = (gid >> 4) / 9;
  int co  = t2 & 127;
  int rb  = t2 >> 7;                         // 0..31
  float o0=0.f,o1=0.f,o2=0.f,o3=0.f;
  #pragma unroll
  for (int e = 0; e < E_; ++e) {
    float rv = rw[rb*E_ + e];
    const float* wp = W1 + (size_t)((e*C2_ + co)*C_ + cq4*4)*9 + s;
    o0 += rv*wp[0]; o1 += rv*wp[9]; o2 += rv*wp[18]; o3 += rv*wp[27];
  }
  f16x4 pk; pk[0]=(f16_t)o0; pk[1]=(f16_t)o1; pk[2]=(f16_t)o2; pk[3]=(f16_t)o3;
  int coh = co >> 6, co6 = co & 63;
  int cb  = cq4 >> 3;
  int cqu = (cq4 >> 1) & 3;
  int off = (cq4 & 1) * 4;
  size_t row = ((size_t)(rb*2 + coh)*2 + cb)*64 + co6;
  *(f16x4*)&w1m[row*288 + (size_t)(s*4 + (cqu ^ sig(co6)))*8 + off] = pk;
}

// ---------- mix2 (+inline srw): w2m row = (b*4+it)*64+co, 288 f16/row -------
__global__ void k_mix2(const float* __restrict__ pooled, const float* __restrict__ srW,
                       const float* __restrict__ srb, const float* __restrict__ W2,
                       f16_t* __restrict__ w2m, size_t w2m_stride, int r0) {
  const int r = r0 + blockIdx.y;
  const float* pooled_r = pooled + (size_t)r*B_*C2_;
  f16_t* w2m_r = w2m + (size_t)r*w2m_stride;
  __shared__ float sw[64];
  int t = threadIdx.x;
  if (t < 64) {
    int b = t >> 3, e = t & 7;
    float acc = srb[e];
    for (int c = 0; c < C2_; ++c)
      acc += pooled_r[b*C2_ + c] * (1.0f/16384.0f) * srW[c*E_ + e];
    sw[t] = acc;
  }
  __syncthreads();
  int gid = blockIdx.x*256 + t;              // 147456 total
  int c2q = gid & 31;                        // ch quad
  int s   = (gid >> 5) % 9;
  int t2  = (gid >> 5) / 9;
  int co  = t2 & 63;
  int b   = t2 >> 6;
  float o0=0.f,o1=0.f,o2=0.f,o3=0.f;
  #pragma unroll
  for (int e = 0; e < E_; ++e) {
    float rv = sw[b*E_ + e];
    const float* wp = W2 + (size_t)((e*C_ + co)*C2_ + c2q*4)*9 + s;
    o0 += rv*wp[0]; o1 += rv*wp[9]; o2 += rv*wp[18]; o3 += rv*wp[27];
  }
  f16x4 pk; pk[0]=(f16_t)o0; pk[1]=(f16_t)o1; pk[2]=(f16_t)o2; pk[3]=(f16_t)o3;
  int it  = c2q >> 3;
  int cqu = (c2q >> 1) & 3;
  int off = (c2q & 1) * 4;
  size_t row = ((size_t)b*4 + it)*64 + co;
  *(f16x4*)&w2m_r[row*288 + (size_t)(s*4 + (cqu ^ sig(co)))*8 + off] = pk;
}

// ---------- conv1: block (b, coh, 3 rows, r): M=64 x N=384 x K=576 ----------
// 3 waves, wave = one output row, tile 64co x 128pix (fn=8).
__global__ __launch_bounds__(192, 2) void k_conv1(
    const f16_t* __restrict__ xbt, const f16_t* __restrict__ w1m,
    const float* __restrict__ pa, f16_t* __restrict__ xct, size_t xct_stride,
    float* __restrict__ pooled, int r0)
{
  const int bx = blockIdx.x;
  const int b = bx & 7;                          // b low bits -> XCD pin
  const int bh = bx >> 3;                        // 0..42
  const int h0 = (bh < 42) ? 3*bh : 125;         // tail: rows 125..127 (125 dup)
  const int coh = blockIdx.y;
  const int r = r0 + blockIdx.z;
  f16_t* xct_r = xct + (size_t)blockIdx.z*xct_stride;
  float* pooled_r = pooled + (size_t)r*B_*C2_;
  const int tid = threadIdx.x;
  const int lane = tid & 63;
  const int wid = tid >> 6;                      // output row 0..2
  const int l15 = lane & 15, l4 = lane >> 4;
  __shared__ __align__(16) f16_t lA[64*288];     // 36,864 B
  __shared__ __align__(16) f16_t lB[2600*8];     // 41,600 B (total 78,464)

  const int xorA = (l4 ^ sig(l15)) << 4;
  int xorB[3];
  #pragma unroll
  for (int dw = 0; dw < 3; ++dw) xorB[dw] = (l4 ^ sig(l15 + dw)) << 4;

  f32x4 acc[4][8];
  #pragma unroll
  for (int i=0;i<4;++i)
    #pragma unroll
    for (int j=0;j<8;++j) acc[i][j] = (f32x4){0.f,0.f,0.f,0.f};

  const int rb = r*B_ + b;
  const f16_t* w1base = w1m + ((size_t)(rb*2 + coh)*2)*64*288;
  const f16_t* xb = xbt + ((size_t)(b*HP_ + h0))*WP_*C_;   // padded row h0 = input h0-1

  for (int cb = 0; cb < 2; ++cb) {
    __syncthreads();                   // previous chunk fully read
    // stage A: 2304 units (64co x 288 f16)
    #pragma unroll
    for (int k = 0; k < 12; ++k) {
      int u = k*192 + tid;
      gl16(w1base + (size_t)cb*64*288 + (size_t)u*8, &lA[u*8]);
    }
    // stage B: 2600 units = 5 rows x 130 pix x 4 quads, sig-swizzled source
    #pragma unroll
    for (int k = 0; k < 13; ++k) {
      int u = k*192 + tid;
      int lr = u / 520, rem = u - lr*520;
      int pix = rem >> 2, cq = (rem & 3) ^ sig(pix);
      gl16(xb + ((size_t)lr*WP_ + pix)*C_ + cb*32 + cq*8, &lB[u*8]);
    }
    if (tid < 104) {
      int u = 2496 + tid;
      int lr = u / 520, rem = u - lr*520;
      int pix = rem >> 2, cq = (rem & 3) ^ sig(pix);
      gl16(xb + ((size_t)lr*WP_ + pix)*C_ + cb*32 + cq*8, &lB[u*8]);
    }
    __syncthreads();                   // vmcnt drain + visibility
    __builtin_amdgcn_s_setprio(1);
    #pragma unroll
    for (int s = 0; s < 9; ++s) {
      const int dh = s / 3, dw = s % 3;
      f16x8 af[4];
      #pragma unroll
      for (int fm = 0; fm < 4; ++fm)
        af[fm] = *(const f16x8*)((const char*)lA + (fm*16 + l15)*576 + s*64 + xorA);
      const char* bb = (const char*)lB + (wid + dh)*8320 + (l15 + dw)*64 + xorB[dw];
      f16x8 bf[8];
      #pragma unroll
      for (int fn = 0; fn < 8; ++fn)
        bf[fn] = *(const f16x8*)(bb + fn*1024);
      #pragma unroll
      for (int fm = 0; fm < 4; ++fm)
        #pragma unroll
        for (int fn = 0; fn < 8; ++fn)
          acc[fm][fn] = mfma16(af[fm], bf[fn], acc[fm][fn]);
    }
    __builtin_amdgcn_s_setprio(0);
  }

  // epilogue: PReLU, pooled (suppress duplicated row), LDS-transpose store
  const float a = pa[0];
  float ps[4][4];
  #pragma unroll
  for (int fm=0;fm<4;++fm)
    #pragma unroll
    for (int j=0;j<4;++j) ps[fm][j] = 0.f;
  #pragma unroll
  for (int fm = 0; fm < 4; ++fm)
    #pragma unroll
    for (int fn = 0; fn < 8; ++fn)
      #pragma unroll
      for (int j = 0; j < 4; ++j) {
        float v = acc[fm][fn][j];
        v = (v >= 0.f) ? v : a*v;
        acc[fm][fn][j] = v;
        ps[fm][j] += v;
      }
  const bool skipPool = (h0 == 125) && (wid == 0);   // row 125 dup of block 41
  #pragma unroll
  for (int fm = 0; fm < 4; ++fm)
    #pragma unroll
    for (int j = 0; j < 4; ++j) {
      float s = ps[fm][j];
      s += __shfl_xor(s, 1, 64);
      s += __shfl_xor(s, 2, 64);
      s += __shfl_xor(s, 4, 64);
      s += __shfl_xor(s, 8, 64);
      if (l15 == 0 && !skipPool)
        atomicAdd(&pooled_r[b*C2_ + coh*64 + fm*16 + l4*4 + j], s);
    }
  // 3 rounds: wave t4 scatters its row to lB [pix 128][72 f16], all copy out
  #pragma unroll
  for (int t4 = 0; t4 < 3; ++t4) {
    __syncthreads();
    if (wid == t4) {
      #pragma unroll
      for (int fm = 0; fm < 4; ++fm)
        #pragma unroll
        for (int fn = 0; fn < 8; ++fn) {
          f16x4 pk;
          #pragma unroll
          for (int j = 0; j < 4; ++j) pk[j] = (f16_t)acc[fm][fn][j];
          int pix = fn*16 + l15;
          *(f16x4*)((char*)lB + pix*144 + (fm*16 + l4*4)*2) = pk;
        }
    }
    __syncthreads();
    #pragma unroll
    for (int k = 0; k < 6; ++k) {
      int u = k*192 + tid;             // 1024 units = 128 pix x 8 octets
      if (u < 1024) {
        int pix = u >> 3, q = u & 7;
        f16x8 v = *(const f16x8*)((const char*)lB + pix*144 + q*16);
        *(f16x8*)(xct_r + ((size_t)(b*HP_ + h0 + t4 + 1)*WP_ + pix + 1)*C2_ + coh*64 + q*8) = v;
      }
    }
  }
}

// ---------- conv2 + PReLU + 1x1 Wout: block (b, 3 rows, r): 64 x 384 x 1152 -
__global__ __launch_bounds__(192, 2) void k_conv2(
    const f16_t* __restrict__ xct, size_t xct_stride,
    const f16_t* __restrict__ w2m, size_t w2m_stride,
    const float* __restrict__ pa, const float* __restrict__ Wout,
    const float* __restrict__ bout, float* __restrict__ out, int r0)
{
  const int bx = blockIdx.x;
  const int b = bx & 7;
  const int bh = bx >> 3;
  const int h0 = (bh < 42) ? 3*bh : 125;         // tail duplicates row 125 (benign)
  const int r = r0 + blockIdx.y;
  const int tid = threadIdx.x;
  const int lane = tid & 63;
  const int wid = tid >> 6;                      // output row 0..2
  const int l15 = lane & 15, l4 = lane >> 4;
  __shared__ __align__(16) f16_t lA[64*288];     // 36,864 B
  __shared__ __align__(16) f16_t lB[2600*8];     // 41,600 B

  const int xorA = (l4 ^ sig(l15)) << 4;
  int xorB[3];
  #pragma unroll
  for (int dw = 0; dw < 3; ++dw) xorB[dw] = (l4 ^ sig(l15 + dw)) << 4;

  f32x4 acc[4][8];
  #pragma unroll
  for (int i=0;i<4;++i)
    #pragma unroll
    for (int j=0;j<8;++j) acc[i][j] = (f32x4){0.f,0.f,0.f,0.f};

  const f16_t* w2base = w2m + (size_t)r*w2m_stride + (size_t)b*4*64*288;
  const f16_t* xb = xct + (size_t)blockIdx.y*xct_stride + ((size_t)(b*HP_ + h0))*WP_*C2_;

  for (int it = 0; it < 4; ++it) {     // K chunks of 32 ch (over 128)
    __syncthreads();
    #pragma unroll
    for (int k = 0; k < 12; ++k) {
      int u = k*192 + tid;
      gl16(w2base + (size_t)it*64*288 + (size_t)u*8, &lA[u*8]);
    }
    #pragma unroll
    for (int k = 0; k < 13; ++k) {
      int u = k*192 + tid;
      int lr = u / 520, rem = u - lr*520;
      int pix = rem >> 2, cq = (rem & 3) ^ sig(pix);
      gl16(xb + ((size_t)lr*WP_ + pix)*C2_ + it*32 + cq*8, &lB[u*8]);
    }
    if (tid < 104) {
      int u = 2496 + tid;
      int lr = u / 520, rem = u - lr*520;
      int pix = rem >> 2, cq = (rem & 3) ^ sig(pix);
      gl16(xb + ((size_t)lr*WP_ + pix)*C2_ + it*32 + cq*8, &lB[u*8]);
    }
    __syncthreads();
    __builtin_amdgcn_s_setprio(1);
    #pragma unroll
    for (int s = 0; s < 9; ++s) {
      const int dh = s / 3, dw = s % 3;
      f16x8 af[4];
      #pragma unroll
      for (int fm = 0; fm < 4; ++fm)
        af[fm] = *(const f16x8*)((const char*)lA + (fm*16 + l15)*576 + s*64 + xorA);
      const char* bb = (const char*)lB + (wid + dh)*8320 + (l15 + dw)*64 + xorB[dw];
      f16x8 bf[8];
      #pragma unroll
      for (int fn = 0; fn < 8; ++fn)
        bf[fn] = *(const f16x8*)(bb + fn*1024);
      #pragma unroll
      for (int fm = 0; fm < 4; ++fm)
        #pragma unroll
        for (int fn = 0; fn < 8; ++fn)
          acc[fm][fn] = mfma16(af[fm], bf[fn], acc[fm][fn]);
    }
    __builtin_amdgcn_s_setprio(0);
  }

  // epilogue: PReLU + Wout reduce -> out[b][r][h0+wid][*]
  const float a  = pa[0];
  const float bo = bout[0];
  float wr_[4][4];
  #pragma unroll
  for (int fm = 0; fm < 4; ++fm)
    #pragma unroll
    for (int j = 0; j < 4; ++j)
      wr_[fm][j] = Wout[fm*16 + l4*4 + j];
  float* orow = out + ((size_t)((b*R_ + r)*H_ + h0 + wid))*W_;
  #pragma unroll
  for (int fn = 0; fn < 8; ++fn) {
    float s = 0.f;
    #pragma unroll
    for (int fm = 0; fm < 4; ++fm)
      #pragma unroll
      for (int j = 0; j < 4; ++j) {
        float v = acc[fm][fn][j];
        v = (v >= 0.f) ? v : a*v;
        s += wr_[fm][j]*v;
      }
    s += __shfl_xor(s, 16, 64);
    s += __shfl_xor(s, 32, 64);
    if (lane < 16)
      orow[fn*16 + lane] = s + bo;
  }
}

// ---------------------------------------------------------------------------
extern "C" void kernel_launch(void* const* d_in, const int* in_sizes, int n_in,
                              void* d_out, int out_size, void* d_ws, size_t ws_size,
                              hipStream_t stream) {
  (void)in_sizes; (void)n_in; (void)out_size;
  const float* x       = (const float*)d_in[0];
  const float* routing = (const float*)d_in[1];
  const float* rW      = (const float*)d_in[2];
  const float* rB      = (const float*)d_in[3];
  const float* W1      = (const float*)d_in[4];
  const float* pa      = (const float*)d_in[5];
  const float* W2      = (const float*)d_in[6];
  const float* srW     = (const float*)d_in[7];
  const float* srb     = (const float*)d_in[8];
  const float* Wout    = (const float*)d_in[9];
  const float* bout    = (const float*)d_in[10];
  float* out = (float*)d_out;

  const size_t xct_one = (size_t)B_*HP_*WP_*C2_;   // elems (34,611,200 B)
  const size_t w2m_one = (size_t)2048*288;         // elems ( 1,179,648 B)
  const size_t need_fused = 17305600ull + 4718592ull + 4*xct_one*2 + 4*w2m_one*2 + 32768ull;
  const bool fused = (ws_size >= need_fused);
  const int ncopies = fused ? 4 : 1;
  const size_t xs = fused ? xct_one : 0;
  const size_t ws2 = fused ? w2m_one : 0;

  char* ws = (char*)d_ws;
  size_t off = 0;
  f16_t* xbt = (f16_t*)(ws + off); off += (size_t)B_*HP_*WP_*C_*2;   // 17,305,600
  f16_t* w1m = (f16_t*)(ws + off); off += (size_t)8192*288*2;        //  4,718,592
  f16_t* xct = (f16_t*)(ws + off); off += xct_one*2*ncopies;
  f16_t* w2m = (f16_t*)(ws + off); off += w2m_one*2*ncopies;
  float* rw     = (float*)(ws + off); off += (size_t)R_*B_*E_*4;
  float* pooled = (float*)(ws + off); off += (size_t)R_*B_*C2_*4;

  k_rw  <<<1, 256, 0, stream>>>(routing, rW, rB, rw, pooled);
  k_zero<<<1097, 256, 0, stream>>>(xbt, xct, xs);
  k_xt  <<<dim3(2, H_, B_), 256, 0, stream>>>(x, xbt);
  k_mix1<<<2304, 256, 0, stream>>>(rw, W1, w1m);
  if (fused) {
    k_conv1<<<dim3(344, 2, 4), 192, 0, stream>>>(xbt, w1m, pa, xct, xs, pooled, 0);
    k_mix2 <<<dim3(576, 4), 256, 0, stream>>>(pooled, srW, srb, W2, w2m, ws2, 0);
    k_conv2<<<dim3(344, 4), 192, 0, stream>>>(xct, xs, w2m, ws2, pa, Wout, bout, out, 0);
  } else {
    for (int r = 0; r < R_; ++r) {
      k_conv1<<<dim3(344, 2, 1), 192, 0, stream>>>(xbt, w1m, pa, xct, xs, pooled, r);
      k_mix2 <<<dim3(576, 1), 256, 0, stream>>>(pooled, srW, srb, W2, w2m, ws2, r);
      k_conv2<<<dim3(344, 1), 192, 0, stream>>>(xct, xs, w2m, ws2, pa, Wout, bout, out, r);
    }
  }
}

// Round 11
// 365.810 us; speedup vs baseline: 1.0386x; 1.0386x over previous
//
#include <hip/hip_runtime.h>
#include <stdint.h>

// ---------------------------------------------------------------------------
// DynamicConv (CondConv x2 + PReLU + self-routing + 1x1 out), MI355X gfx950
// R11: R6 structure with fn=8 wave tiles (64co x 128pix) in 2-row/2-wave/
//      128-thr blocks, launch_bounds(128,1) -> 512-reg budget (no spill),
//      LDS 70.1KB -> 2 blocks/CU. Same barriers/staging as R6.
// ---------------------------------------------------------------------------

typedef _Float16 f16_t;
typedef _Float16 f16x8 __attribute__((ext_vector_type(8)));
typedef _Float16 f16x4 __attribute__((ext_vector_type(4)));
typedef float    f32x4 __attribute__((ext_vector_type(4)));

#define B_   8
#define R_   4
#define C_   64
#define C2_  128
#define H_   128
#define W_   128
#define E_   8
#define RF_  256
#define WP_  130   // padded width  (guard cols at pix 0 and 129)
#define HP_  130   // padded height (guard rows at hp 0 and 129)

__device__ __forceinline__ f32x4 mfma16(f16x8 a, f16x8 b, f32x4 c) {
  return __builtin_amdgcn_mfma_f32_16x16x32_f16(a, b, c, 0, 0, 0);
}

// async global->LDS, 16B per lane; dest wave-linear (base + lane*16)
__device__ __forceinline__ void gl16(const f16_t* g, f16_t* l) {
  __builtin_amdgcn_global_load_lds(
      (const __attribute__((address_space(1))) unsigned int*)(const void*)g,
      (__attribute__((address_space(3))) unsigned int*)(void*)l, 16, 0, 0);
}

__device__ __host__ __forceinline__ int sig(int n) { return (n ^ (n >> 2)) & 3; }

// ---------- routing weights + zero pooled[4][B][C2] ----------
__global__ void k_rw(const float* __restrict__ routing, const float* __restrict__ rW,
                     const float* __restrict__ rB, float* __restrict__ rw,
                     float* __restrict__ pooled4) {
  int t = threadIdx.x;                 // 256 = R*B*E
  #pragma unroll
  for (int i = 0; i < 16; ++i) pooled4[i*256 + t] = 0.f;
  int e = t & 7, b = (t >> 3) & 7, r = t >> 6;
  float acc = rB[e];
  for (int f = 0; f < RF_; ++f)
    acc += routing[(b*R_ + r)*RF_ + f] * rW[f*E_ + e];
  rw[(r*B_ + b)*E_ + e] = 1.0f / (1.0f + __expf(-acc));
}

// ---------- zero guard rows/cols of xbt and all-r xct (130x130) --------------
__global__ void k_zero(f16_t* __restrict__ xbt, f16_t* __restrict__ xct,
                       size_t xct_stride) {
  const f16x8 z = {0,0,0,0,0,0,0,0};
  int t = blockIdx.x*256 + threadIdx.x;
  if (t < 16640) {                       // xbt guard rows: 8b*2*130pix*8slots
    int ch = t & 7, u = t >> 3;
    int pix = u % 130; u /= 130;
    int rs = u & 1, b = u >> 1;
    *(f16x8*)&xbt[((size_t)(b*HP_ + rs*129)*WP_ + pix)*C_ + ch*8] = z;
    return;
  }
  t -= 16640;
  if (t < 133120) {                      // xct guard rows: 4r*8b*2*130pix*16slots
    int ch = t & 15, u = t >> 4;
    int pix = u % 130; u /= 130;
    int rs = u & 1; u >>= 1;
    int b = u & 7, r = u >> 3;
    *(f16x8*)&xct[(size_t)r*xct_stride + ((size_t)(b*HP_ + rs*129)*WP_ + pix)*C2_ + ch*8] = z;
    return;
  }
  t -= 133120;
  if (t < 131072) {                      // xct guard cols: 4r*8b*128row*2*16slots
    int ch = t & 15, u = t >> 4;
    int hp = (u & 127) + 1; u >>= 7;
    int cs = u & 1; u >>= 1;
    int b = u & 7, r = u >> 3;
    *(f16x8*)&xct[(size_t)r*xct_stride + ((size_t)(b*HP_ + hp)*WP_ + cs*129)*C2_ + ch*8] = z;
  }
}

// ---------- x: NCHW f32 -> padded NHWC f16 (interior rows; guard cols) ------
__global__ void k_xt(const float* __restrict__ x, f16_t* __restrict__ xbt) {
  int wh = blockIdx.x, h = blockIdx.y, b = blockIdx.z;
  int t = threadIdx.x;
  int w0 = wh * 64;
  __shared__ float tile[64][65];
  #pragma unroll
  for (int rep = 0; rep < 16; ++rep) {
    int idx = rep*256 + t;
    int c = idx >> 6, w = idx & 63;
    tile[c][w] = x[((size_t)(b*C_ + c)*H_ + h)*W_ + w0 + w];
  }
  __syncthreads();
  #pragma unroll
  for (int rep = 0; rep < 16; ++rep) {
    int idx = rep*256 + t;
    int w = idx >> 6, c = idx & 63;
    xbt[((size_t)(b*HP_ + h + 1)*WP_ + (w0 + w + 1))*C_ + c] = (f16_t)tile[c][w];
  }
  if (t < 64) {
    if (wh == 0) xbt[((size_t)(b*HP_ + h + 1)*WP_ + 0)*C_ + t]   = (f16_t)0.0f;
    else         xbt[((size_t)(b*HP_ + h + 1)*WP_ + 129)*C_ + t] = (f16_t)0.0f;
  }
}

// ---------- mix1: w1m row = ((rb*2+coh)*2+cb)*64+co6, 288 f16/row -----------
__global__ void k_mix1(const float* __restrict__ rw, const float* __restrict__ W1,
                       f16_t* __restrict__ w1m) {
  int gid = blockIdx.x*256 + threadIdx.x;    // 589824 total
  int cq4 = gid & 15;                        // ch quad: ch = cq4*4 .. +3
  int s   = (gid >> 4) % 9;
  int t2  = (gid >> 4) / 9;
  int co  = t2 & 127;
  int rb  = t2 >> 7;                         // 0..31
  float o0=0.f,o1=0.f,o2=0.f,o3=0.f;
  #pragma unroll
  for (int e = 0; e < E_; ++e) {
    float rv = rw[rb*E_ + e];
    const float* wp = W1 + (size_t)((e*C2_ + co)*C_ + cq4*4)*9 + s;
    o0 += rv*wp[0]; o1 += rv*wp[9]; o2 += rv*wp[18]; o3 += rv*wp[27];
  }
  f16x4 pk; pk[0]=(f16_t)o0; pk[1]=(f16_t)o1; pk[2]=(f16_t)o2; pk[3]=(f16_t)o3;
  int coh = co >> 6, co6 = co & 63;
  int cb  = cq4 >> 3;
  int cqu = (cq4 >> 1) & 3;
  int off = (cq4 & 1) * 4;
  size_t row = ((size_t)(rb*2 + coh)*2 + cb)*64 + co6;
  *(f16x4*)&w1m[row*288 + (size_t)(s*4 + (cqu ^ sig(co6)))*8 + off] = pk;
}

// ---------- mix2 (+inline srw): w2m row = (b*4+it)*64+co, 288 f16/row -------
__global__ void k_mix2(const float* __restrict__ pooled, const float* __restrict__ srW,
                       const float* __restrict__ srb, const float* __restrict__ W2,
                       f16_t* __restrict__ w2m, size_t w2m_stride, int r0) {
  const int r = r0 + blockIdx.y;
  const float* pooled_r = pooled + (size_t)r*B_*C2_;
  f16_t* w2m_r = w2m + (size_t)r*w2m_stride;
  __shared__ float sw[64];
  int t = threadIdx.x;
  if (t < 64) {
    int b = t >> 3, e = t & 7;
    float acc = srb[e];
    for (int c = 0; c < C2_; ++c)
      acc += pooled_r[b*C2_ + c] * (1.0f/16384.0f) * srW[c*E_ + e];
    sw[t] = acc;
  }
  __syncthreads();
  int gid = blockIdx.x*256 + t;              // 147456 total
  int c2q = gid & 31;                        // ch quad
  int s   = (gid >> 5) % 9;
  int t2  = (gid >> 5) / 9;
  int co  = t2 & 63;
  int b   = t2 >> 6;
  float o0=0.f,o1=0.f,o2=0.f,o3=0.f;
  #pragma unroll
  for (int e = 0; e < E_; ++e) {
    float rv = sw[b*E_ + e];
    const float* wp = W2 + (size_t)((e*C_ + co)*C2_ + c2q*4)*9 + s;
    o0 += rv*wp[0]; o1 += rv*wp[9]; o2 += rv*wp[18]; o3 += rv*wp[27];
  }
  f16x4 pk; pk[0]=(f16_t)o0; pk[1]=(f16_t)o1; pk[2]=(f16_t)o2; pk[3]=(f16_t)o3;
  int it  = c2q >> 3;
  int cqu = (c2q >> 1) & 3;
  int off = (c2q & 1) * 4;
  size_t row = ((size_t)b*4 + it)*64 + co;
  *(f16x4*)&w2m_r[row*288 + (size_t)(s*4 + (cqu ^ sig(co)))*8 + off] = pk;
}

// ---------- conv1: block (b, coh, 2 rows, r): M=64 x N=256 x K=576 ----------
// 2 waves, wave = one output row, tile 64co x 128pix (fn=8).
__global__ __launch_bounds__(128, 1) void k_conv1(
    const f16_t* __restrict__ xbt, const f16_t* __restrict__ w1m,
    const float* __restrict__ pa, f16_t* __restrict__ xct, size_t xct_stride,
    float* __restrict__ pooled, int r0)
{
  const int bx = blockIdx.x;
  const int b = bx & 7, h0 = (bx >> 3) << 1;     // b low bits -> XCD pin
  const int coh = blockIdx.y;
  const int r = r0 + blockIdx.z;
  f16_t* xct_r = xct + (size_t)blockIdx.z*xct_stride;
  float* pooled_r = pooled + (size_t)r*B_*C2_;
  const int tid = threadIdx.x;
  const int lane = tid & 63;
  const int wid = tid >> 6;                      // output row 0..1
  const int l15 = lane & 15, l4 = lane >> 4;
  __shared__ __align__(16) f16_t lA[64*288];     // 36,864 B
  __shared__ __align__(16) f16_t lB[2080*8];     // 33,280 B (total 70,144)

  const int xorA = (l4 ^ sig(l15)) << 4;
  int xorB[3];
  #pragma unroll
  for (int dw = 0; dw < 3; ++dw)
    xorB[dw] = (l15 + dw)*64 + ((l4 ^ sig(l15 + dw)) << 4);

  f32x4 acc[4][8];
  #pragma unroll
  for (int i=0;i<4;++i)
    #pragma unroll
    for (int j=0;j<8;++j) acc[i][j] = (f32x4){0.f,0.f,0.f,0.f};

  const int rb = r*B_ + b;
  const f16_t* w1base = w1m + ((size_t)(rb*2 + coh)*2)*64*288;
  const f16_t* xb = xbt + ((size_t)(b*HP_ + h0))*WP_*C_;

  for (int cb = 0; cb < 2; ++cb) {
    __syncthreads();                   // previous chunk fully read
    // stage A: 2304 units (64co x 288 f16), linear
    #pragma unroll
    for (int k = 0; k < 18; ++k) {
      int u = k*128 + tid;
      gl16(w1base + (size_t)cb*64*288 + (size_t)u*8, &lA[u*8]);
    }
    // stage B: 2080 units = 4 rows x 130 pix x 4 quads, sig-swizzled source
    #pragma unroll
    for (int k = 0; k < 16; ++k) {
      int u = k*128 + tid;
      int lr = u / 520, rem = u - lr*520;
      int pix = rem >> 2, cq = (rem & 3) ^ sig(pix);
      gl16(xb + ((size_t)lr*WP_ + pix)*C_ + cb*32 + cq*8, &lB[u*8]);
    }
    if (tid < 32) {                    // tail 32 units (row 3)
      int u = 2048 + tid;
      int rem = u - 1560;
      int pix = rem >> 2, cq = (rem & 3) ^ sig(pix);
      gl16(xb + ((size_t)3*WP_ + pix)*C_ + cb*32 + cq*8, &lB[u*8]);
    }
    __syncthreads();                   // vmcnt drain + visibility
    __builtin_amdgcn_s_setprio(1);
    #pragma unroll
    for (int s = 0; s < 9; ++s) {
      const int dh = s / 3, dw = s % 3;
      f16x8 af[4];
      #pragma unroll
      for (int fm = 0; fm < 4; ++fm)
        af[fm] = *(const f16x8*)((const char*)lA + (fm*16 + l15)*576 + s*64 + xorA);
      const char* bb = (const char*)lB + (wid + dh)*8320 + xorB[dw];
      f16x8 bf[8];
      #pragma unroll
      for (int fn = 0; fn < 8; ++fn)
        bf[fn] = *(const f16x8*)(bb + fn*1024);
      #pragma unroll
      for (int fm = 0; fm < 4; ++fm)
        #pragma unroll
        for (int fn = 0; fn < 8; ++fn)
          acc[fm][fn] = mfma16(af[fm], bf[fn], acc[fm][fn]);
    }
    __builtin_amdgcn_s_setprio(0);
  }

  // epilogue: PReLU, pooled atomics, 2-round LDS transpose -> coalesced xct
  const float a = pa[0];
  float ps[4][4];
  #pragma unroll
  for (int fm=0;fm<4;++fm)
    #pragma unroll
    for (int j=0;j<4;++j) ps[fm][j] = 0.f;
  #pragma unroll
  for (int fm = 0; fm < 4; ++fm)
    #pragma unroll
    for (int fn = 0; fn < 8; ++fn)
      #pragma unroll
      for (int j = 0; j < 4; ++j) {
        float v = acc[fm][fn][j];
        v = (v >= 0.f) ? v : a*v;
        acc[fm][fn][j] = v;
        ps[fm][j] += v;
      }
  #pragma unroll
  for (int fm = 0; fm < 4; ++fm)
    #pragma unroll
    for (int j = 0; j < 4; ++j) {
      float s = ps[fm][j];
      s += __shfl_xor(s, 1, 64);
      s += __shfl_xor(s, 2, 64);
      s += __shfl_xor(s, 4, 64);
      s += __shfl_xor(s, 8, 64);
      if (l15 == 0)
        atomicAdd(&pooled_r[b*C2_ + coh*64 + fm*16 + l4*4 + j], s);
    }
  // 2 rounds: wave t scatters its row to lB [pix 128][72 f16], both copy out
  #pragma unroll
  for (int t4 = 0; t4 < 2; ++t4) {
    __syncthreads();
    if (wid == t4) {
      #pragma unroll
      for (int fm = 0; fm < 4; ++fm)
        #pragma unroll
        for (int fn = 0; fn < 8; ++fn) {
          f16x4 pk;
          #pragma unroll
          for (int j = 0; j < 4; ++j) pk[j] = (f16_t)acc[fm][fn][j];
          int pix = fn*16 + l15;
          *(f16x4*)((char*)lB + pix*144 + (fm*16 + l4*4)*2) = pk;
        }
    }
    __syncthreads();
    #pragma unroll
    for (int k = 0; k < 8; ++k) {
      int u = k*128 + tid;             // 1024 units = 128 pix x 8 octets
      int pix = u >> 3, q = u & 7;
      f16x8 v = *(const f16x8*)((const char*)lB + pix*144 + q*16);
      *(f16x8*)(xct_r + ((size_t)(b*HP_ + h0 + t4 + 1)*WP_ + pix + 1)*C2_ + coh*64 + q*8) = v;
    }
  }
}

// ---------- conv2 + PReLU + 1x1 Wout: block (b, 2 rows, r): 64 x 256 x 1152 -
__global__ __launch_bounds__(128, 1) void k_conv2(
    const f16_t* __restrict__ xct, size_t xct_stride,
    const f16_t* __restrict__ w2m, size_t w2m_stride,
    const float* __restrict__ pa, const float* __restrict__ Wout,
    const float* __restrict__ bout, float* __restrict__ out, int r0)
{
  const int bx = blockIdx.x;
  const int b = bx & 7, h0 = (bx >> 3) << 1;
  const int r = r0 + blockIdx.y;
  const int tid = threadIdx.x;
  const int lane = tid & 63;
  const int wid = tid >> 6;                      // output row 0..1
  const int l15 = lane & 15, l4 = lane >> 4;
  __shared__ __align__(16) f16_t lA[64*288];     // 36,864 B
  __shared__ __align__(16) f16_t lB[2080*8];     // 33,280 B

  const int xorA = (l4 ^ sig(l15)) << 4;
  int xorB[3];
  #pragma unroll
  for (int dw = 0; dw < 3; ++dw)
    xorB[dw] = (l15 + dw)*64 + ((l4 ^ sig(l15 + dw)) << 4);

  f32x4 acc[4][8];
  #pragma unroll
  for (int i=0;i<4;++i)
    #pragma unroll
    for (int j=0;j<8;++j) acc[i][j] = (f32x4){0.f,0.f,0.f,0.f};

  const f16_t* w2base = w2m + (size_t)r*w2m_stride + (size_t)b*4*64*288;
  const f16_t* xb = xct + (size_t)blockIdx.y*xct_stride + ((size_t)(b*HP_ + h0))*WP_*C2_;

  for (int it = 0; it < 4; ++it) {     // K chunks of 32 ch (over 128)
    __syncthreads();
    #pragma unroll
    for (int k = 0; k < 18; ++k) {
      int u = k*128 + tid;
      gl16(w2base + (size_t)it*64*288 + (size_t)u*8, &lA[u*8]);
    }
    #pragma unroll
    for (int k = 0; k < 16; ++k) {
      int u = k*128 + tid;
      int lr = u / 520, rem = u - lr*520;
      int pix = rem >> 2, cq = (rem & 3) ^ sig(pix);
      gl16(xb + ((size_t)lr*WP_ + pix)*C2_ + it*32 + cq*8, &lB[u*8]);
    }
    if (tid < 32) {
      int u = 2048 + tid;
      int rem = u - 1560;
      int pix = rem >> 2, cq = (rem & 3) ^ sig(pix);
      gl16(xb + ((size_t)3*WP_ + pix)*C2_ + it*32 + cq*8, &lB[u*8]);
    }
    __syncthreads();
    __builtin_amdgcn_s_setprio(1);
    #pragma unroll
    for (int s = 0; s < 9; ++s) {
      const int dh = s / 3, dw = s % 3;
      f16x8 af[4];
      #pragma unroll
      for (int fm = 0; fm < 4; ++fm)
        af[fm] = *(const f16x8*)((const char*)lA + (fm*16 + l15)*576 + s*64 + xorA);
      const char* bb = (const char*)lB + (wid + dh)*8320 + xorB[dw];
      f16x8 bf[8];
      #pragma unroll
      for (int fn = 0; fn < 8; ++fn)
        bf[fn] = *(const f16x8*)(bb + fn*1024);
      #pragma unroll
      for (int fm = 0; fm < 4; ++fm)
        #pragma unroll
        for (int fn = 0; fn < 8; ++fn)
          acc[fm][fn] = mfma16(af[fm], bf[fn], acc[fm][fn]);
    }
    __builtin_amdgcn_s_setprio(0);
  }

  // epilogue: PReLU + Wout reduce -> out[b][r][h0+wid][*]
  const float a  = pa[0];
  const float bo = bout[0];
  float wr_[4][4];
  #pragma unroll
  for (int fm = 0; fm < 4; ++fm)
    #pragma unroll
    for (int j = 0; j < 4; ++j)
      wr_[fm][j] = Wout[fm*16 + l4*4 + j];
  float* orow = out + ((size_t)((b*R_ + r)*H_ + h0 + wid))*W_;
  #pragma unroll
  for (int fn = 0; fn < 8; ++fn) {
    float s = 0.f;
    #pragma unroll
    for (int fm = 0; fm < 4; ++fm)
      #pragma unroll
      for (int j = 0; j < 4; ++j) {
        float v = acc[fm][fn][j];
        v = (v >= 0.f) ? v : a*v;
        s += wr_[fm][j]*v;
      }
    s += __shfl_xor(s, 16, 64);
    s += __shfl_xor(s, 32, 64);
    if (lane < 16)
      orow[fn*16 + lane] = s + bo;
  }
}

// ---------------------------------------------------------------------------
extern "C" void kernel_launch(void* const* d_in, const int* in_sizes, int n_in,
                              void* d_out, int out_size, void* d_ws, size_t ws_size,
                              hipStream_t stream) {
  (void)in_sizes; (void)n_in; (void)out_size;
  const float* x       = (const float*)d_in[0];
  const float* routing = (const float*)d_in[1];
  const float* rW      = (const float*)d_in[2];
  const float* rB      = (const float*)d_in[3];
  const float* W1      = (const float*)d_in[4];
  const float* pa      = (const float*)d_in[5];
  const float* W2      = (const float*)d_in[6];
  const float* srW     = (const float*)d_in[7];
  const float* srb     = (const float*)d_in[8];
  const float* Wout    = (const float*)d_in[9];
  const float* bout    = (const float*)d_in[10];
  float* out = (float*)d_out;

  const size_t xct_one = (size_t)B_*HP_*WP_*C2_;   // elems (34,611,200 B)
  const size_t w2m_one = (size_t)2048*288;         // elems ( 1,179,648 B)
  const size_t need_fused = 17305600ull + 4718592ull + 4*xct_one*2 + 4*w2m_one*2 + 32768ull;
  const bool fused = (ws_size >= need_fused);
  const int ncopies = fused ? 4 : 1;
  const size_t xs = fused ? xct_one : 0;
  const size_t ws2 = fused ? w2m_one : 0;

  char* ws = (char*)d_ws;
  size_t off = 0;
  f16_t* xbt = (f16_t*)(ws + off); off += (size_t)B_*HP_*WP_*C_*2;   // 17,305,600
  f16_t* w1m = (f16_t*)(ws + off); off += (size_t)8192*288*2;        //  4,718,592
  f16_t* xct = (f16_t*)(ws + off); off += xct_one*2*ncopies;
  f16_t* w2m = (f16_t*)(ws + off); off += w2m_one*2*ncopies;
  float* rw     = (float*)(ws + off); off += (size_t)R_*B_*E_*4;
  float* pooled = (float*)(ws + off); off += (size_t)R_*B_*C2_*4;

  k_rw  <<<1, 256, 0, stream>>>(routing, rW, rB, rw, pooled);
  k_zero<<<1097, 256, 0, stream>>>(xbt, xct, xs);
  k_xt  <<<dim3(2, H_, B_), 256, 0, stream>>>(x, xbt);
  k_mix1<<<2304, 256, 0, stream>>>(rw, W1, w1m);
  if (fused) {
    k_conv1<<<dim3(512, 2, 4), 128, 0, stream>>>(xbt, w1m, pa, xct, xs, pooled, 0);
    k_mix2 <<<dim3(576, 4), 256, 0, stream>>>(pooled, srW, srb, W2, w2m, ws2, 0);
    k_conv2<<<dim3(512, 4), 128, 0, stream>>>(xct, xs, w2m, ws2, pa, Wout, bout, out, 0);
  } else {
    for (int r = 0; r < R_; ++r) {
      k_conv1<<<dim3(512, 2, 1), 128, 0, stream>>>(xbt, w1m, pa, xct, xs, pooled, r);
      k_mix2 <<<dim3(576, 1), 256, 0, stream>>>(pooled, srW, srb, W2, w2m, ws2, r);
      k_conv2<<<dim3(512, 1), 128, 0, stream>>>(xct, xs, w2m, ws2, pa, Wout, bout, out, r);
    }
  }
}

// Round 12
// 335.910 us; speedup vs baseline: 1.1310x; 1.0890x over previous
//
#include <hip/hip_runtime.h>
#include <stdint.h>

// ---------------------------------------------------------------------------
// DynamicConv (CondConv x2 + PReLU + self-routing + 1x1 out), MI355X gfx950
// R12: 8-wave single-block-per-CU pipelined kernels. fn=8 wave tiles,
//      per-(cb,dh) A sub-chunks double-buffered (issue-next-then-compute),
//      B dbuf (conv1) / single (conv2). perm-XOR A layout, sig-swizzle B.
// ---------------------------------------------------------------------------

typedef _Float16 f16_t;
typedef _Float16 f16x8 __attribute__((ext_vector_type(8)));
typedef _Float16 f16x4 __attribute__((ext_vector_type(4)));
typedef float    f32x4 __attribute__((ext_vector_type(4)));

#define B_   8
#define R_   4
#define C_   64
#define C2_  128
#define H_   128
#define W_   128
#define E_   8
#define RF_  256
#define WP_  130
#define HP_  130

__device__ __forceinline__ f32x4 mfma16(f16x8 a, f16x8 b, f32x4 c) {
  return __builtin_amdgcn_mfma_f32_16x16x32_f16(a, b, c, 0, 0, 0);
}

__device__ __forceinline__ void gl16(const f16_t* g, f16_t* l) {
  __builtin_amdgcn_global_load_lds(
      (const __attribute__((address_space(1))) unsigned int*)(const void*)g,
      (__attribute__((address_space(3))) unsigned int*)(void*)l, 16, 0, 0);
}

__device__ __host__ __forceinline__ int sig(int n) { return (n ^ (n >> 2)) & 3; }
__device__ __host__ __forceinline__ int perm(int q) { return ((q & 1) << 4) | ((q >> 1) << 3); }

// ---------- routing weights + zero pooled[4][B][C2] ----------
__global__ void k_rw(const float* __restrict__ routing, const float* __restrict__ rW,
                     const float* __restrict__ rB, float* __restrict__ rw,
                     float* __restrict__ pooled4) {
  int t = threadIdx.x;                 // 256 = R*B*E
  #pragma unroll
  for (int i = 0; i < 16; ++i) pooled4[i*256 + t] = 0.f;
  int e = t & 7, b = (t >> 3) & 7, r = t >> 6;
  float acc = rB[e];
  for (int f = 0; f < RF_; ++f)
    acc += routing[(b*R_ + r)*RF_ + f] * rW[f*E_ + e];
  rw[(r*B_ + b)*E_ + e] = 1.0f / (1.0f + __expf(-acc));
}

// ---------- zero guard rows/cols of xbt and all-r xct (130x130) --------------
__global__ void k_zero(f16_t* __restrict__ xbt, f16_t* __restrict__ xct,
                       size_t xct_stride) {
  const f16x8 z = {0,0,0,0,0,0,0,0};
  int t = blockIdx.x*256 + threadIdx.x;
  if (t < 16640) {
    int ch = t & 7, u = t >> 3;
    int pix = u % 130; u /= 130;
    int rs = u & 1, b = u >> 1;
    *(f16x8*)&xbt[((size_t)(b*HP_ + rs*129)*WP_ + pix)*C_ + ch*8] = z;
    return;
  }
  t -= 16640;
  if (t < 133120) {
    int ch = t & 15, u = t >> 4;
    int pix = u % 130; u /= 130;
    int rs = u & 1; u >>= 1;
    int b = u & 7, r = u >> 3;
    *(f16x8*)&xct[(size_t)r*xct_stride + ((size_t)(b*HP_ + rs*129)*WP_ + pix)*C2_ + ch*8] = z;
    return;
  }
  t -= 133120;
  if (t < 131072) {
    int ch = t & 15, u = t >> 4;
    int hp = (u & 127) + 1; u >>= 7;
    int cs = u & 1; u >>= 1;
    int b = u & 7, r = u >> 3;
    *(f16x8*)&xct[(size_t)r*xct_stride + ((size_t)(b*HP_ + hp)*WP_ + cs*129)*C2_ + ch*8] = z;
  }
}

// ---------- x: NCHW f32 -> padded NHWC f16 (interior rows; guard cols) ------
__global__ void k_xt(const float* __restrict__ x, f16_t* __restrict__ xbt) {
  int wh = blockIdx.x, h = blockIdx.y, b = blockIdx.z;
  int t = threadIdx.x;
  int w0 = wh * 64;
  __shared__ float tile[64][65];
  #pragma unroll
  for (int rep = 0; rep < 16; ++rep) {
    int idx = rep*256 + t;
    int c = idx >> 6, w = idx & 63;
    tile[c][w] = x[((size_t)(b*C_ + c)*H_ + h)*W_ + w0 + w];
  }
  __syncthreads();
  #pragma unroll
  for (int rep = 0; rep < 16; ++rep) {
    int idx = rep*256 + t;
    int w = idx >> 6, c = idx & 63;
    xbt[((size_t)(b*HP_ + h + 1)*WP_ + (w0 + w + 1))*C_ + c] = (f16_t)tile[c][w];
  }
  if (t < 64) {
    if (wh == 0) xbt[((size_t)(b*HP_ + h + 1)*WP_ + 0)*C_ + t]   = (f16_t)0.0f;
    else         xbt[((size_t)(b*HP_ + h + 1)*WP_ + 129)*C_ + t] = (f16_t)0.0f;
  }
}

// ---------- mix1: w1m units [rb][cb2][dh3][dw3][q4][co128 ^perm(q)] ---------
__global__ void k_mix1(const float* __restrict__ rw, const float* __restrict__ W1,
                       f16_t* __restrict__ w1m) {
  int gid = blockIdx.x*256 + threadIdx.x;    // 589824 total
  int cq4 = gid & 15;
  int s   = (gid >> 4) % 9;
  int t2  = (gid >> 4) / 9;
  int co  = t2 & 127;
  int rb  = t2 >> 7;
  float o0=0.f,o1=0.f,o2=0.f,o3=0.f;
  #pragma unroll
  for (int e = 0; e < E_; ++e) {
    float rv = rw[rb*E_ + e];
    const float* wp = W1 + (size_t)((e*C2_ + co)*C_ + cq4*4)*9 + s;
    o0 += rv*wp[0]; o1 += rv*wp[9]; o2 += rv*wp[18]; o3 += rv*wp[27];
  }
  f16x4 pk; pk[0]=(f16_t)o0; pk[1]=(f16_t)o1; pk[2]=(f16_t)o2; pk[3]=(f16_t)o3;
  int cb   = cq4 >> 3;
  int q    = (cq4 >> 1) & 3;
  int half = cq4 & 1;
  size_t unit = (size_t)rb*9216 + (size_t)(cb*9 + s)*512 + q*128 + (co ^ perm(q));
  *(f16x4*)&w1m[unit*8 + half*4] = pk;
}

// ---------- mix2 (+srw): w2m units [r][b][it4][dh3][dw3][q4][co64 ^perm(q)] -
__global__ void k_mix2(const float* __restrict__ pooled, const float* __restrict__ srW,
                       const float* __restrict__ srb, const float* __restrict__ W2,
                       f16_t* __restrict__ w2m, size_t w2m_stride, int r0) {
  const int r = r0 + blockIdx.y;
  const float* pooled_r = pooled + (size_t)r*B_*C2_;
  f16_t* w2m_r = w2m + (size_t)r*w2m_stride;
  __shared__ float sw[64];
  int t = threadIdx.x;
  if (t < 64) {
    int b = t >> 3, e = t & 7;
    float acc = srb[e];
    for (int c = 0; c < C2_; ++c)
      acc += pooled_r[b*C2_ + c] * (1.0f/16384.0f) * srW[c*E_ + e];
    sw[t] = acc;
  }
  __syncthreads();
  int gid = blockIdx.x*256 + t;              // 147456 total
  int c2q = gid & 31;
  int s   = (gid >> 5) % 9;
  int t2  = (gid >> 5) / 9;
  int co  = t2 & 63;
  int b   = t2 >> 6;
  float o0=0.f,o1=0.f,o2=0.f,o3=0.f;
  #pragma unroll
  for (int e = 0; e < E_; ++e) {
    float rv = sw[b*E_ + e];
    const float* wp = W2 + (size_t)((e*C_ + co)*C2_ + c2q*4)*9 + s;
    o0 += rv*wp[0]; o1 += rv*wp[9]; o2 += rv*wp[18]; o3 += rv*wp[27];
  }
  f16x4 pk; pk[0]=(f16_t)o0; pk[1]=(f16_t)o1; pk[2]=(f16_t)o2; pk[3]=(f16_t)o3;
  int it   = c2q >> 3;
  int q    = (c2q >> 1) & 3;
  int half = c2q & 1;
  size_t unit = (size_t)b*9216 + (size_t)(it*9 + s)*256 + q*64 + (co ^ perm(q));
  *(f16x4*)&w2m_r[unit*8 + half*4] = pk;
}

// ---------- conv1: block (b, 4 rows, r): M=128 x N=512 x K=576 --------------
// 8 waves: wrow=wid>>1 (row), wm=wid&1 (co-half); wave tile 64co x 128pix.
__global__ __launch_bounds__(512, 1) void k_conv1(
    const f16_t* __restrict__ xbt, const f16_t* __restrict__ w1m,
    const float* __restrict__ pa, f16_t* __restrict__ xct, size_t xct_stride,
    float* __restrict__ pooled, int r0)
{
  const int bx = blockIdx.x;
  const int b = bx & 7, h0 = (bx >> 3) << 2;
  const int r = r0 + blockIdx.z;
  f16_t* xct_r = xct + (size_t)blockIdx.z*xct_stride;
  float* pooled_r = pooled + (size_t)r*B_*C2_;
  const int tid = threadIdx.x;
  const int lane = tid & 63;
  const int wid = tid >> 6;
  const int wrow = wid >> 1, wm = wid & 1;
  const int l15 = lane & 15, l4 = lane >> 4;
  __shared__ __align__(16) f16_t lA[2][1536*8];   // 24,576 B x2
  __shared__ __align__(16) f16_t lB[2][3120*8];   // 49,920 B x2  (total 148,992)

  int aoff[4];
  #pragma unroll
  for (int fm = 0; fm < 4; ++fm)
    aoff[fm] = l4*2048 + (((wm*64 + fm*16 + l15) ^ perm(l4)) << 4);
  int boff[3];
  #pragma unroll
  for (int dw = 0; dw < 3; ++dw)
    boff[dw] = (((l15 + dw)*4 + (l4 ^ sig(l15 + dw))) << 4);

  f32x4 acc[4][8];
  #pragma unroll
  for (int i=0;i<4;++i)
    #pragma unroll
    for (int j=0;j<8;++j) acc[i][j] = (f32x4){0.f,0.f,0.f,0.f};

  const f16_t* w1base = w1m + (size_t)(r*B_ + b)*9216*8;
  const f16_t* xb = xbt + ((size_t)(b*HP_ + h0))*WP_*C_;

  #define STAGE_A1(buf, ph) {                                              \
    int base_ = ((ph)/3)*4608 + ((ph)%3)*1536;                             \
    _Pragma("unroll")                                                      \
    for (int k_ = 0; k_ < 3; ++k_) {                                       \
      int u_ = k_*512 + tid;                                               \
      gl16(w1base + (size_t)(base_ + u_)*8, &lA[buf][u_*8]);               \
    } }
  #define STAGE_B1(buf, cb) {                                              \
    _Pragma("unroll")                                                      \
    for (int k_ = 0; k_ < 6; ++k_) {                                       \
      int u_ = k_*512 + tid;                                               \
      int lr_ = u_/520, rem_ = u_ - lr_*520;                               \
      int pix_ = rem_ >> 2, cq_ = (rem_ & 3) ^ sig(pix_);                  \
      gl16(xb + ((size_t)lr_*WP_ + pix_)*C_ + (cb)*32 + cq_*8, &lB[buf][u_*8]); \
    }                                                                      \
    if (tid < 48) {                                                        \
      int u_ = 3072 + tid;                                                 \
      int rem_ = u_ - 2600;                                                \
      int pix_ = rem_ >> 2, cq_ = (rem_ & 3) ^ sig(pix_);                  \
      gl16(xb + ((size_t)5*WP_ + pix_)*C_ + (cb)*32 + cq_*8, &lB[buf][u_*8]); \
    } }

  STAGE_B1(0, 0);
  STAGE_A1(0, 0);
  __syncthreads();

  int ab = 0;
  for (int cb = 0; cb < 2; ++cb) {
    for (int dh = 0; dh < 3; ++dh) {
      const int p = cb*3 + dh;
      if (p == 0) { STAGE_B1(1, 1); }
      if (p < 5)  { STAGE_A1(ab^1, p+1); }
      const char* Ab = (const char*)lA[ab];
      const char* Bb = (const char*)lB[cb];
      __builtin_amdgcn_s_setprio(1);
      #pragma unroll
      for (int dw = 0; dw < 3; ++dw) {
        f16x8 af[4], bf[8];
        #pragma unroll
        for (int fm = 0; fm < 4; ++fm)
          af[fm] = *(const f16x8*)(Ab + dw*8192 + aoff[fm]);
        const char* bb = Bb + (wrow + dh)*8320 + boff[dw];
        #pragma unroll
        for (int fn = 0; fn < 8; ++fn)
          bf[fn] = *(const f16x8*)(bb + fn*1024);
        #pragma unroll
        for (int fm = 0; fm < 4; ++fm)
          #pragma unroll
          for (int fn = 0; fn < 8; ++fn)
            acc[fm][fn] = mfma16(af[fm], bf[fn], acc[fm][fn]);
      }
      __builtin_amdgcn_s_setprio(0);
      __syncthreads();
      ab ^= 1;
    }
  }

  // epilogue: PReLU, pooled atomics, 4-round LDS transpose -> coalesced xct
  const float a = pa[0];
  float ps[4][4];
  #pragma unroll
  for (int fm=0;fm<4;++fm)
    #pragma unroll
    for (int j=0;j<4;++j) ps[fm][j] = 0.f;
  #pragma unroll
  for (int fm = 0; fm < 4; ++fm)
    #pragma unroll
    for (int fn = 0; fn < 8; ++fn)
      #pragma unroll
      for (int j = 0; j < 4; ++j) {
        float v = acc[fm][fn][j];
        v = (v >= 0.f) ? v : a*v;
        acc[fm][fn][j] = v;
        ps[fm][j] += v;
      }
  #pragma unroll
  for (int fm = 0; fm < 4; ++fm)
    #pragma unroll
    for (int j = 0; j < 4; ++j) {
      float s = ps[fm][j];
      s += __shfl_xor(s, 1, 64);
      s += __shfl_xor(s, 2, 64);
      s += __shfl_xor(s, 4, 64);
      s += __shfl_xor(s, 8, 64);
      if (l15 == 0)
        atomicAdd(&pooled_r[b*C2_ + wm*64 + fm*16 + l4*4 + j], s);
    }
  char* lso = (char*)&lB[0][0];        // [128 pix][336 B]
  #pragma unroll
  for (int t4 = 0; t4 < 4; ++t4) {
    __syncthreads();
    if (wrow == t4) {
      #pragma unroll
      for (int fm = 0; fm < 4; ++fm)
        #pragma unroll
        for (int fn = 0; fn < 8; ++fn) {
          f16x4 pk;
          #pragma unroll
          for (int j = 0; j < 4; ++j) pk[j] = (f16_t)acc[fm][fn][j];
          int pix = fn*16 + l15;
          *(f16x4*)(lso + pix*336 + wm*160 + (fm*16 + l4*4)*2) = pk;
        }
    }
    __syncthreads();
    #pragma unroll
    for (int k = 0; k < 4; ++k) {
      int idx = tid + 512*k;
      int pix = idx >> 4, u = idx & 15;
      f16x8 v = *(const f16x8*)(lso + pix*336 + u*16 + ((u >= 8) ? 32 : 0));
      *(f16x8*)(xct_r + ((size_t)(b*HP_ + h0 + t4 + 1)*WP_ + pix + 1)*C2_ + u*8) = v;
    }
  }
  #undef STAGE_A1
  #undef STAGE_B1
}

// ---------- conv2 + PReLU + 1x1 Wout: block (b, 8 rows, r): 64 x 1024 x 1152
__global__ __launch_bounds__(512, 1) void k_conv2(
    const f16_t* __restrict__ xct, size_t xct_stride,
    const f16_t* __restrict__ w2m, size_t w2m_stride,
    const float* __restrict__ pa, const float* __restrict__ Wout,
    const float* __restrict__ bout, float* __restrict__ out, int r0)
{
  const int bx = blockIdx.x;
  const int b = bx & 7, h0 = (bx >> 3) << 3;
  const int r = r0 + blockIdx.y;
  const int tid = threadIdx.x;
  const int lane = tid & 63;
  const int wid = tid >> 6;                      // output row 0..7
  const int l15 = lane & 15, l4 = lane >> 4;
  __shared__ __align__(16) f16_t lA[2][768*8];   // 12,288 B x2
  __shared__ __align__(16) f16_t lB[5200*8];     // 83,200 B (total 107,776)

  int aoff[4];
  #pragma unroll
  for (int fm = 0; fm < 4; ++fm)
    aoff[fm] = l4*1024 + (((fm*16 + l15) ^ perm(l4)) << 4);
  int boff[3];
  #pragma unroll
  for (int dw = 0; dw < 3; ++dw)
    boff[dw] = (((l15 + dw)*4 + (l4 ^ sig(l15 + dw))) << 4);

  f32x4 acc[4][8];
  #pragma unroll
  for (int i=0;i<4;++i)
    #pragma unroll
    for (int j=0;j<8;++j) acc[i][j] = (f32x4){0.f,0.f,0.f,0.f};

  const f16_t* w2base = w2m + (size_t)r*w2m_stride + (size_t)b*9216*8;
  const f16_t* xb = xct + (size_t)blockIdx.y*xct_stride + ((size_t)(b*HP_ + h0))*WP_*C2_;

  #define STAGE_A2(buf, ph) {                                              \
    int base_ = ((ph)/3)*2304 + ((ph)%3)*768;                              \
    { int u_ = tid;                                                        \
      gl16(w2base + (size_t)(base_ + u_)*8, &lA[buf][u_*8]); }             \
    if (tid < 256) { int u_ = 512 + tid;                                   \
      gl16(w2base + (size_t)(base_ + u_)*8, &lA[buf][u_*8]); } }
  #define STAGE_B2(it) {                                                   \
    _Pragma("unroll")                                                      \
    for (int k_ = 0; k_ < 10; ++k_) {                                      \
      int u_ = k_*512 + tid;                                               \
      int lr_ = u_/520, rem_ = u_ - lr_*520;                               \
      int pix_ = rem_ >> 2, cq_ = (rem_ & 3) ^ sig(pix_);                  \
      gl16(xb + ((size_t)lr_*WP_ + pix_)*C2_ + (it)*32 + cq_*8, &lB[u_*8]); \
    }                                                                      \
    if (tid < 80) {                                                        \
      int u_ = 5120 + tid;                                                 \
      int rem_ = u_ - 4680;                                                \
      int pix_ = rem_ >> 2, cq_ = (rem_ & 3) ^ sig(pix_);                  \
      gl16(xb + ((size_t)9*WP_ + pix_)*C2_ + (it)*32 + cq_*8, &lB[u_*8]);  \
    } }

  STAGE_A2(0, 0);
  int ab = 0;
  for (int it = 0; it < 4; ++it) {
    // previous phase's barrier guarantees all reads of lB done
    STAGE_B2(it);
    __syncthreads();                   // drain B (+ pending A)
    for (int dh = 0; dh < 3; ++dh) {
      const int p = it*3 + dh;
      if (p < 11) { STAGE_A2(ab^1, p+1); }
      const char* Ab = (const char*)lA[ab];
      __builtin_amdgcn_s_setprio(1);
      #pragma unroll
      for (int dw = 0; dw < 3; ++dw) {
        f16x8 af[4], bf[8];
        #pragma unroll
        for (int fm = 0; fm < 4; ++fm)
          af[fm] = *(const f16x8*)(Ab + dw*4096 + aoff[fm]);
        const char* bb = (const char*)lB + (wid + dh)*8320 + boff[dw];
        #pragma unroll
        for (int fn = 0; fn < 8; ++fn)
          bf[fn] = *(const f16x8*)(bb + fn*1024);
        #pragma unroll
        for (int fm = 0; fm < 4; ++fm)
          #pragma unroll
          for (int fn = 0; fn < 8; ++fn)
            acc[fm][fn] = mfma16(af[fm], bf[fn], acc[fm][fn]);
      }
      __builtin_amdgcn_s_setprio(0);
      __syncthreads();
      ab ^= 1;
    }
  }

  // epilogue: PReLU + Wout reduce -> out[b][r][h0+wid][*]
  const float a  = pa[0];
  const float bo = bout[0];
  float wr_[4][4];
  #pragma unroll
  for (int fm = 0; fm < 4; ++fm)
    #pragma unroll
    for (int j = 0; j < 4; ++j)
      wr_[fm][j] = Wout[fm*16 + l4*4 + j];
  float* orow = out + ((size_t)((b*R_ + r)*H_ + h0 + wid))*W_;
  #pragma unroll
  for (int fn = 0; fn < 8; ++fn) {
    float s = 0.f;
    #pragma unroll
    for (int fm = 0; fm < 4; ++fm)
      #pragma unroll
      for (int j = 0; j < 4; ++j) {
        float v = acc[fm][fn][j];
        v = (v >= 0.f) ? v : a*v;
        s += wr_[fm][j]*v;
      }
    s += __shfl_xor(s, 16, 64);
    s += __shfl_xor(s, 32, 64);
    if (lane < 16)
      orow[fn*16 + lane] = s + bo;
  }
  #undef STAGE_A2
  #undef STAGE_B2
}

// ---------------------------------------------------------------------------
extern "C" void kernel_launch(void* const* d_in, const int* in_sizes, int n_in,
                              void* d_out, int out_size, void* d_ws, size_t ws_size,
                              hipStream_t stream) {
  (void)in_sizes; (void)n_in; (void)out_size;
  const float* x       = (const float*)d_in[0];
  const float* routing = (const float*)d_in[1];
  const float* rW      = (const float*)d_in[2];
  const float* rB      = (const float*)d_in[3];
  const float* W1      = (const float*)d_in[4];
  const float* pa      = (const float*)d_in[5];
  const float* W2      = (const float*)d_in[6];
  const float* srW     = (const float*)d_in[7];
  const float* srb     = (const float*)d_in[8];
  const float* Wout    = (const float*)d_in[9];
  const float* bout    = (const float*)d_in[10];
  float* out = (float*)d_out;

  const size_t xct_one = (size_t)B_*HP_*WP_*C2_;   // elems (34,611,200 B)
  const size_t w2m_one = (size_t)8*9216*8;         // elems per r (1,179,648 B)
  const size_t need_fused = 17305600ull + 4718592ull + 4*xct_one*2 + 4*w2m_one*2 + 32768ull;
  const bool fused = (ws_size >= need_fused);
  const int ncopies = fused ? 4 : 1;
  const size_t xs = fused ? xct_one : 0;
  const size_t ws2 = fused ? w2m_one : 0;

  char* ws = (char*)d_ws;
  size_t off = 0;
  f16_t* xbt = (f16_t*)(ws + off); off += (size_t)B_*HP_*WP_*C_*2;   // 17,305,600
  f16_t* w1m = (f16_t*)(ws + off); off += (size_t)32*9216*16;        //  4,718,592
  f16_t* xct = (f16_t*)(ws + off); off += xct_one*2*ncopies;
  f16_t* w2m = (f16_t*)(ws + off); off += w2m_one*2*ncopies;
  float* rw     = (float*)(ws + off); off += (size_t)R_*B_*E_*4;
  float* pooled = (float*)(ws + off); off += (size_t)R_*B_*C2_*4;

  k_rw  <<<1, 256, 0, stream>>>(routing, rW, rB, rw, pooled);
  k_zero<<<1097, 256, 0, stream>>>(xbt, xct, xs);
  k_xt  <<<dim3(2, H_, B_), 256, 0, stream>>>(x, xbt);
  k_mix1<<<2304, 256, 0, stream>>>(rw, W1, w1m);
  if (fused) {
    k_conv1<<<dim3(256, 1, 4), 512, 0, stream>>>(xbt, w1m, pa, xct, xs, pooled, 0);
    k_mix2 <<<dim3(576, 4), 256, 0, stream>>>(pooled, srW, srb, W2, w2m, ws2, 0);
    k_conv2<<<dim3(128, 4), 512, 0, stream>>>(xct, xs, w2m, ws2, pa, Wout, bout, out, 0);
  } else {
    for (int r = 0; r < R_; ++r) {
      k_conv1<<<dim3(256, 1, 1), 512, 0, stream>>>(xbt, w1m, pa, xct, xs, pooled, r);
      k_mix2 <<<dim3(576, 1), 256, 0, stream>>>(pooled, srW, srb, W2, w2m, ws2, r);
      k_conv2<<<dim3(128, 1), 512, 0, stream>>>(xct, xs, w2m, ws2, pa, Wout, bout, out, r);
    }
  }
}